// Round 7
// baseline (741.687 us; speedup 1.0000x reference)
//
#include <hip/hip_runtime.h>
#include <math.h>

// ---------------------------------------------------------------------------
// MPConv round 9: sorted path with PARALLEL aux kernels.
// R6 lesson: launch count (2-8) is ~free; R2's sort overhead was the serial
// single-block scan. Plan: hist -> 2-level parallel scan -> packed int4 edge
// table {e,src,dst} -> run-reduced-scatter main (proven 343us, WRITE 31MB).
//   L1 prep_all   : zero out + zero counts + W->bf16^T + x->bf16
//   L2 hist_dst   : counts[dst]++
//   L3 scan_local : per-256-block exclusive scan -> offs(local), bsum
//   L4 scan_tops  : single block scans bsum -> boff   (nb <= 1024)
//   L5 build_etri : pos = atomicAdd(offs[dst]) + boff[dst>>8];
//                   etri[pos] = {e, src, dst, 0}  (one 16B scattered store)
//   L6 mpconv_sorted: GEMM1 -> LN+GELU -> GEMM2 -> run-reduced scatter
// Fallback (ws too small / nb>1024): proven R6 2-launch direct-atomic path.
// ---------------------------------------------------------------------------

using short8 = __attribute__((ext_vector_type(8))) short;
using f32x4  = __attribute__((ext_vector_type(4))) float;

#define LDH 72        // bf16 H-tile stride (64+8)
#define WREG 9472     // per-wave LDS: max(64*72*2, 32*66*4)=9216 + 64*4 dstL
#define SMEM_BYTES (4 * WREG)   // 37,888

static __device__ __forceinline__ short f2bf(float f) {
    unsigned u = __float_as_uint(f);
    u += 0x7FFFu + ((u >> 16) & 1u);        // round-to-nearest-even
    return (short)(u >> 16);
}

static __device__ __forceinline__ short8 pack8(float4 a, float4 b) {
    short8 r;
    r[0] = f2bf(a.x); r[1] = f2bf(a.y); r[2] = f2bf(a.z); r[3] = f2bf(a.w);
    r[4] = f2bf(b.x); r[5] = f2bf(b.y); r[6] = f2bf(b.z); r[7] = f2bf(b.w);
    return r;
}

// ---- L1: zero out + zero counts + weights -> bf16 [n][k] + x -> bf16 ------
__global__ __launch_bounds__(256) void prep_all(
    const float* __restrict__ x,      // [N,64]
    const float* __restrict__ W1,     // [160,64]
    const float* __restrict__ W2,     // [64,64]
    short* __restrict__ Wt1,          // [64][160]
    short* __restrict__ Wt2,          // [64][64]
    short* __restrict__ xbf,          // [N][64]
    int*   __restrict__ counts,       // [N] (may be null if !doSort)
    float* __restrict__ out,
    int N, int out_elems, int doX, int doSort)
{
    const int tid = blockIdx.x * 256 + threadIdx.x;
    const int TT  = gridDim.x * 256;

    const int nf4 = out_elems >> 2;
    const float4 z = make_float4(0.f, 0.f, 0.f, 0.f);
    for (int i = tid; i < nf4; i += TT) ((float4*)out)[i] = z;
    for (int i = (nf4 << 2) + tid; i < out_elems; i += TT) out[i] = 0.f;

    if (doSort)
        for (int i = tid; i < N; i += TT) counts[i] = 0;

    for (int t = tid; t < 160 * 64; t += TT) {
        int k = t / 64, n = t % 64;
        Wt1[n * 160 + k] = f2bf(W1[t]);
    }
    for (int t = tid; t < 64 * 64; t += TT) {
        int k = t / 64, n = t % 64;
        Wt2[n * 64 + k] = f2bf(W2[t]);
    }
    if (doX) {
        const float4* xf4 = (const float4*)x;
        for (int t = tid; t < N * 8; t += TT) {
            float4 a = xf4[2 * t];
            float4 b = xf4[2 * t + 1];
            ((short8*)xbf)[t] = pack8(a, b);
        }
    }
}

// ---- L2: histogram of destinations ----------------------------------------
__global__ void hist_dst(const int* __restrict__ ei, int* __restrict__ counts, int E)
{
    int e = blockIdx.x * blockDim.x + threadIdx.x;
    if (e < E) atomicAdd(&counts[ei[E + e]], 1);
}

// ---- L3: per-block exclusive scan (256 elems/block) ------------------------
__global__ __launch_bounds__(256) void scan_local(const int* __restrict__ counts,
                                                  int* __restrict__ offs,
                                                  int* __restrict__ bsum, int N)
{
    __shared__ int sc[256];
    const int t = threadIdx.x;
    const int i = blockIdx.x * 256 + t;
    int v = (i < N) ? counts[i] : 0;
    sc[t] = v;
    __syncthreads();
    for (int d = 1; d < 256; d <<= 1) {
        int u = (t >= d) ? sc[t - d] : 0;
        __syncthreads();
        sc[t] += u;
        __syncthreads();
    }
    if (i < N) offs[i] = sc[t] - v;          // local exclusive
    if (t == 255) bsum[blockIdx.x] = sc[255];
}

// ---- L4: single-block scan of block sums -> boff (nb <= 1024) --------------
__global__ __launch_bounds__(1024) void scan_tops(const int* __restrict__ bsum,
                                                  int* __restrict__ boff, int nb)
{
    __shared__ int sc[1024];
    const int t = threadIdx.x;
    int v = (t < nb) ? bsum[t] : 0;
    sc[t] = v;
    __syncthreads();
    for (int d = 1; d < 1024; d <<= 1) {
        int u = (t >= d) ? sc[t - d] : 0;
        __syncthreads();
        sc[t] += u;
        __syncthreads();
    }
    if (t < nb) boff[t] = sc[t] - v;         // exclusive over blocks
}

// ---- L5: build packed dst-sorted edge table --------------------------------
__global__ void build_etri(const int* __restrict__ ei, int* __restrict__ offs,
                           const int* __restrict__ boff,
                           int4* __restrict__ etri, int E)
{
    int e = blockIdx.x * blockDim.x + threadIdx.x;
    if (e < E) {
        int src = ei[e];
        int dst = ei[E + e];
        int pos = atomicAdd(&offs[dst], 1) + boff[dst >> 8];
        etri[pos] = make_int4(e, src, dst, 0);
    }
}

// ---- L6: main sorted kernel ------------------------------------------------
__global__ __launch_bounds__(256) void mpconv_sorted(
    const short* __restrict__ xbf,    // [N][64] bf16
    const float* __restrict__ ea,     // [E,32]
    const short* __restrict__ Wt1,    // [64][160] bf16
    const float* __restrict__ b1,
    const float* __restrict__ gam,
    const float* __restrict__ bet,
    const short* __restrict__ Wt2,    // [64][64] bf16
    const float* __restrict__ b2,
    const int4*  __restrict__ etri,   // [E] {e, src, dst, 0} dst-sorted
    float*       __restrict__ out,    // [N,64]
    int E)
{
    __shared__ __align__(16) char smem[SMEM_BYTES];

    const int wave = threadIdx.x >> 6;
    const int lane = threadIdx.x & 63;
    const int g    = lane >> 4;
    const int col  = lane & 15;
    const int eb   = blockIdx.x * 256 + wave * 64;     // sorted-edge base

    char* wbase = smem + wave * WREG;
    short (*Hl)[LDH] = (short (*)[LDH])wbase;   // [64][72] bf16
    float (*Hf)[66]  = (float (*)[66])wbase;    // [32][66] f32 (aliases Hl)
    int*  dstL       = (int*)(wbase + 9216);    // [64]

    // coalesced packed index loads (no dependent random gathers)
    int aedge[4], ii[4], jj[4];
#pragma unroll
    for (int mt = 0; mt < 4; mt++) {
        int ep = eb + mt * 16 + col;
        bool v = (ep < E);
        int epc = v ? ep : (E - 1);
        int4 t4 = etri[epc];
        aedge[mt] = t4.x;
        ii[mt] = t4.y;
        jj[mt] = t4.z;
        if (g == 0) dstL[mt * 16 + col] = v ? t4.z : -1;
    }

    float b1c[4], gc[4], bc[4], b2c[4];
#pragma unroll
    for (int nt = 0; nt < 4; nt++) {
        int c = col + 16 * nt;
        b1c[nt] = b1[c]; gc[nt] = gam[c]; bc[nt] = bet[c]; b2c[nt] = b2[c];
    }

    // ---- GEMM1: [64,160] @ [160,64] -----------------------------------
    f32x4 acc[4][4];
#pragma unroll
    for (int mt = 0; mt < 4; mt++)
#pragma unroll
        for (int nt = 0; nt < 4; nt++)
            acc[mt][nt] = (f32x4){0.f, 0.f, 0.f, 0.f};

#pragma unroll
    for (int ks = 0; ks < 5; ks++) {
        const int k0 = ks * 32;
        const int kk = k0 + g * 8;

        short8 afrag[4];
#pragma unroll
        for (int mt = 0; mt < 4; mt++) {
            if (k0 < 64) {
                afrag[mt] = *(const short8*)(xbf + (size_t)ii[mt] * 64 + kk);
            } else if (k0 < 128) {
                afrag[mt] = *(const short8*)(xbf + (size_t)jj[mt] * 64 + (kk - 64));
            } else {
                const float* s = ea + (size_t)aedge[mt] * 32 + (kk - 128);
                float4 a = *(const float4*)s;
                float4 b = *(const float4*)(s + 4);
                afrag[mt] = pack8(a, b);
            }
        }
        short8 bfrag[4];
#pragma unroll
        for (int nt = 0; nt < 4; nt++)
            bfrag[nt] = *(const short8*)(Wt1 + (size_t)(col + 16 * nt) * 160 + kk);

#pragma unroll
        for (int mt = 0; mt < 4; mt++)
#pragma unroll
            for (int nt = 0; nt < 4; nt++)
                acc[mt][nt] = __builtin_amdgcn_mfma_f32_16x16x32_bf16(
                    afrag[mt], bfrag[nt], acc[mt][nt], 0, 0, 0);
    }

    // ---- +b1, LayerNorm, GELU -> Hl (bf16) ----------------------------
#pragma unroll
    for (int mt = 0; mt < 4; mt++) {
        float s[4] = {0.f, 0.f, 0.f, 0.f};
        float q[4] = {0.f, 0.f, 0.f, 0.f};
#pragma unroll
        for (int nt = 0; nt < 4; nt++) {
#pragma unroll
            for (int r = 0; r < 4; r++) {
                float v = acc[mt][nt][r] + b1c[nt];
                acc[mt][nt][r] = v;
                s[r] += v;
                q[r] += v * v;
            }
        }
#pragma unroll
        for (int m = 1; m < 16; m <<= 1) {
#pragma unroll
            for (int r = 0; r < 4; r++) {
                s[r] += __shfl_xor(s[r], m);
                q[r] += __shfl_xor(q[r], m);
            }
        }
#pragma unroll
        for (int r = 0; r < 4; r++) {
            float mu  = s[r] * (1.0f / 64.0f);
            float var = q[r] * (1.0f / 64.0f) - mu * mu;
            float inv = rsqrtf(var + 1e-5f);
            int row = mt * 16 + g * 4 + r;
#pragma unroll
            for (int nt = 0; nt < 4; nt++) {
                float h = (acc[mt][nt][r] - mu) * inv * gc[nt] + bc[nt];
                h = 0.5f * h * (1.0f + erff(h * 0.70710678118654752f));
                Hl[row][col + 16 * nt] = f2bf(h);
            }
        }
    }
    // per-wave LDS region: no barrier needed (in-order DS per wave)

    // ---- GEMM2: [64,64] @ [64,64] -------------------------------------
    f32x4 acc2[4][4];
#pragma unroll
    for (int mt = 0; mt < 4; mt++)
#pragma unroll
        for (int nt = 0; nt < 4; nt++)
            acc2[mt][nt] = (f32x4){0.f, 0.f, 0.f, 0.f};

#pragma unroll
    for (int ks = 0; ks < 2; ks++) {
        const int kk = ks * 32 + g * 8;
        short8 af[4], bf[4];
#pragma unroll
        for (int mt = 0; mt < 4; mt++)
            af[mt] = *(const short8*)&Hl[mt * 16 + col][kk];
#pragma unroll
        for (int nt = 0; nt < 4; nt++)
            bf[nt] = *(const short8*)(Wt2 + (size_t)(col + 16 * nt) * 64 + kk);
#pragma unroll
        for (int mt = 0; mt < 4; mt++)
#pragma unroll
            for (int nt = 0; nt < 4; nt++)
                acc2[mt][nt] = __builtin_amdgcn_mfma_f32_16x16x32_bf16(
                    af[mt], bf[nt], acc2[mt][nt], 0, 0, 0);
    }

    // ---- run-reduced scatter over dst-sorted rows ----------------------
    int cur = -1;
    float sum = 0.f;
#pragma unroll
    for (int p = 0; p < 2; p++) {
#pragma unroll
        for (int m2 = 0; m2 < 2; m2++) {
            int mt = 2 * p + m2;
#pragma unroll
            for (int nt = 0; nt < 4; nt++)
#pragma unroll
                for (int r = 0; r < 4; r++)
                    Hf[m2 * 16 + g * 4 + r][col + 16 * nt] =
                        acc2[mt][nt][r] + b2c[nt];
        }
#pragma unroll 4
        for (int row = 0; row < 32; row++) {
            int d = dstL[p * 32 + row];          // wave-uniform broadcast
            float v = Hf[row][lane];             // 2-way bank alias: free
            if (d != cur) {                      // uniform branch
                if (cur >= 0)
                    unsafeAtomicAdd(out + (size_t)cur * 64 + lane, sum);
                cur = d; sum = 0.f;
            }
            if (d >= 0) sum += v;
        }
    }
    if (cur >= 0)
        unsafeAtomicAdd(out + (size_t)cur * 64 + lane, sum);
}

// ---- fallback main (R6-proven direct-atomic) -------------------------------
template <bool XBF>
__global__ __launch_bounds__(256) void mpconv_mfma(
    const float* __restrict__ x,
    const short* __restrict__ xbf,
    const int*   __restrict__ ei,
    const float* __restrict__ ea,
    const short* __restrict__ Wt1,
    const float* __restrict__ b1,
    const float* __restrict__ gam,
    const float* __restrict__ bet,
    const short* __restrict__ Wt2,
    const float* __restrict__ b2,
    float*       __restrict__ out,
    int E)
{
    __shared__ __align__(16) short Hlds[4][64][LDH];

    const int wave = threadIdx.x >> 6;
    const int lane = threadIdx.x & 63;
    const int g    = lane >> 4;
    const int col  = lane & 15;
    const int eb   = blockIdx.x * 256 + wave * 64;

    int aedge[4], ii[4], jj[4];
#pragma unroll
    for (int mt = 0; mt < 4; mt++) {
        int e = eb + mt * 16 + col;
        e = (e < E) ? e : (E - 1);
        aedge[mt] = e;
        ii[mt] = ei[e];
        jj[mt] = ei[E + e];
    }

    float b1c[4], gc[4], bc[4], b2c[4];
#pragma unroll
    for (int nt = 0; nt < 4; nt++) {
        int c = col + 16 * nt;
        b1c[nt] = b1[c]; gc[nt] = gam[c]; bc[nt] = bet[c]; b2c[nt] = b2[c];
    }

    f32x4 acc[4][4];
#pragma unroll
    for (int mt = 0; mt < 4; mt++)
#pragma unroll
        for (int nt = 0; nt < 4; nt++)
            acc[mt][nt] = (f32x4){0.f, 0.f, 0.f, 0.f};

#pragma unroll
    for (int ks = 0; ks < 5; ks++) {
        const int k0 = ks * 32;
        const int kk = k0 + g * 8;

        short8 afrag[4];
#pragma unroll
        for (int mt = 0; mt < 4; mt++) {
            if (XBF && k0 < 64) {
                afrag[mt] = *(const short8*)(xbf + (size_t)ii[mt] * 64 + kk);
            } else if (XBF && k0 < 128) {
                afrag[mt] = *(const short8*)(xbf + (size_t)jj[mt] * 64 + (kk - 64));
            } else {
                const float* s;
                if (k0 < 64)       s = x  + (size_t)ii[mt] * 64 + kk;
                else if (k0 < 128) s = x  + (size_t)jj[mt] * 64 + (kk - 64);
                else               s = ea + (size_t)aedge[mt] * 32 + (kk - 128);
                float4 a = *(const float4*)s;
                float4 b = *(const float4*)(s + 4);
                afrag[mt] = pack8(a, b);
            }
        }
        short8 bfrag[4];
#pragma unroll
        for (int nt = 0; nt < 4; nt++)
            bfrag[nt] = *(const short8*)(Wt1 + (size_t)(col + 16 * nt) * 160 + kk);

#pragma unroll
        for (int mt = 0; mt < 4; mt++)
#pragma unroll
            for (int nt = 0; nt < 4; nt++)
                acc[mt][nt] = __builtin_amdgcn_mfma_f32_16x16x32_bf16(
                    afrag[mt], bfrag[nt], acc[mt][nt], 0, 0, 0);
    }

#pragma unroll
    for (int mt = 0; mt < 4; mt++) {
        float s[4] = {0.f, 0.f, 0.f, 0.f};
        float q[4] = {0.f, 0.f, 0.f, 0.f};
#pragma unroll
        for (int nt = 0; nt < 4; nt++) {
#pragma unroll
            for (int r = 0; r < 4; r++) {
                float v = acc[mt][nt][r] + b1c[nt];
                acc[mt][nt][r] = v;
                s[r] += v;
                q[r] += v * v;
            }
        }
#pragma unroll
        for (int m = 1; m < 16; m <<= 1) {
#pragma unroll
            for (int r = 0; r < 4; r++) {
                s[r] += __shfl_xor(s[r], m);
                q[r] += __shfl_xor(q[r], m);
            }
        }
#pragma unroll
        for (int r = 0; r < 4; r++) {
            float mu  = s[r] * (1.0f / 64.0f);
            float var = q[r] * (1.0f / 64.0f) - mu * mu;
            float inv = rsqrtf(var + 1e-5f);
            int row = mt * 16 + g * 4 + r;
#pragma unroll
            for (int nt = 0; nt < 4; nt++) {
                float h = (acc[mt][nt][r] - mu) * inv * gc[nt] + bc[nt];
                h = 0.5f * h * (1.0f + erff(h * 0.70710678118654752f));
                Hlds[wave][row][col + 16 * nt] = f2bf(h);
            }
        }
    }
    __syncthreads();

    f32x4 acc2[4][4];
#pragma unroll
    for (int mt = 0; mt < 4; mt++)
#pragma unroll
        for (int nt = 0; nt < 4; nt++)
            acc2[mt][nt] = (f32x4){0.f, 0.f, 0.f, 0.f};

#pragma unroll
    for (int ks = 0; ks < 2; ks++) {
        const int kk = ks * 32 + g * 8;
        short8 af[4], bf[4];
#pragma unroll
        for (int mt = 0; mt < 4; mt++)
            af[mt] = *(const short8*)&Hlds[wave][mt * 16 + col][kk];
#pragma unroll
        for (int nt = 0; nt < 4; nt++)
            bf[nt] = *(const short8*)(Wt2 + (size_t)(col + 16 * nt) * 64 + kk);
#pragma unroll
        for (int mt = 0; mt < 4; mt++)
#pragma unroll
            for (int nt = 0; nt < 4; nt++)
                acc2[mt][nt] = __builtin_amdgcn_mfma_f32_16x16x32_bf16(
                    af[mt], bf[nt], acc2[mt][nt], 0, 0, 0);
    }

#pragma unroll
    for (int mt = 0; mt < 4; mt++) {
#pragma unroll
        for (int r = 0; r < 4; r++) {
            int e = eb + mt * 16 + g * 4 + r;
            if (e < E) {
                int dst = ei[E + e];
                float* op = out + (size_t)dst * 64 + col;
#pragma unroll
                for (int nt = 0; nt < 4; nt++)
                    unsafeAtomicAdd(op + 16 * nt, acc2[mt][nt][r] + b2c[nt]);
            }
        }
    }
}

// =========================== host launch ===================================
extern "C" void kernel_launch(void* const* d_in, const int* in_sizes, int n_in,
                              void* d_out, int out_size, void* d_ws, size_t ws_size,
                              hipStream_t stream)
{
    const float* x   = (const float*)d_in[0];
    const int*   ei  = (const int*)  d_in[1];
    const float* ea  = (const float*)d_in[2];
    const float* W1  = (const float*)d_in[3];
    const float* b1  = (const float*)d_in[4];
    const float* gam = (const float*)d_in[5];
    const float* bet = (const float*)d_in[6];
    const float* W2  = (const float*)d_in[7];
    const float* b2  = (const float*)d_in[8];
    float* out = (float*)d_out;

    const int E = in_sizes[1] / 2;
    const int N = in_sizes[0] / 64;
    const int nb = (N + 255) / 256;             // scan blocks (<=1024 required)

    // ws layout: Wt1 | Wt2 | xbf | counts | offs | bsum | boff | etri
    short* Wt1 = (short*)d_ws;
    short* Wt2 = Wt1 + 160 * 64;
    const size_t woff = (size_t)(160 * 64 + 64 * 64) * sizeof(short);   // 28,672
    short* xbf = (short*)((char*)d_ws + woff);
    const size_t need_xbf = woff + (size_t)N * 64 * sizeof(short);
    const size_t soff = (need_xbf + 255) & ~(size_t)255;
    int* counts = (int*)((char*)d_ws + soff);
    int* offs   = counts + N;
    int* bsum   = offs + N;
    int* boff   = bsum + 1024;
    const size_t eoff = (soff + (size_t)N * 8 + 8192 + 255) & ~(size_t)255;
    int4* etri  = (int4*)((char*)d_ws + eoff);
    const size_t need_full = eoff + (size_t)E * sizeof(int4);

    const int use_xbf  = (ws_size >= need_xbf) ? 1 : 0;
    const int use_sort = (ws_size >= need_full && nb <= 1024 && use_xbf) ? 1 : 0;

    // L1: fused prep (zero out [+counts] + W->bf16 + x->bf16)
    hipLaunchKernelGGL(prep_all, dim3(2048), dim3(256), 0, stream,
                       x, W1, W2, Wt1, Wt2, xbf, counts, out,
                       N, out_size, use_xbf, use_sort);

    if (use_sort) {
        const int gridE = (E + 255) / 256;
        hipLaunchKernelGGL(hist_dst, dim3(gridE), dim3(256), 0, stream,
                           ei, counts, E);
        hipLaunchKernelGGL(scan_local, dim3(nb), dim3(256), 0, stream,
                           counts, offs, bsum, N);
        hipLaunchKernelGGL(scan_tops, dim3(1), dim3(1024), 0, stream,
                           bsum, boff, nb);
        hipLaunchKernelGGL(build_etri, dim3(gridE), dim3(256), 0, stream,
                           ei, offs, boff, etri, E);
        hipLaunchKernelGGL(mpconv_sorted, dim3(gridE), dim3(256), 0, stream,
                           xbf, ea, Wt1, b1, gam, bet, Wt2, b2, etri, out, E);
    } else {
        const int gridE = (E + 255) / 256;
        if (use_xbf)
            hipLaunchKernelGGL(mpconv_mfma<true>, dim3(gridE), dim3(256), 0, stream,
                               x, xbf, ei, ea, Wt1, b1, gam, bet, Wt2, b2, out, E);
        else
            hipLaunchKernelGGL(mpconv_mfma<false>, dim3(gridE), dim3(256), 0, stream,
                               x, xbf, ei, ea, Wt1, b1, gam, bet, Wt2, b2, out, E);
    }
}